// Round 3
// baseline (157.173 us; speedup 1.0000x reference)
//
#include <hip/hip_runtime.h>

// ---------------------------------------------------------------------------
// AttentionBlock: GroupNorm -> QKV 1x1 conv -> MHA (8 heads, d=64, N=1024)
//               -> proj 1x1 conv -> +residual
// Shapes: B=8, C=512, H=W=32 (N=1024), groups=32, heads=8, hd=64. fp32 I/O.
// R14 == R13 resubmit (container infra failure, kernel audited clean):
// attn kernel restructured: NO dual-kv-split. 4 waves/block, each wave owns
// a 32-q subtile and sweeps ALL 1024 kv (16 tiles); K/V staged once per
// block (LDS 36864B, was 73728), 2 blocks/CU so one block computes through
// the other's barrier. Split-combine epilogue (8KB f32 LDS round-trip + 2
// barriers) deleted -> direct stores. launch_bounds(256,2) lifts the
// 128-VGPR squeeze. T5 setprio around MFMA clusters.
// ---------------------------------------------------------------------------

typedef __bf16 bf16;
typedef __bf16 bf16x8 __attribute__((ext_vector_type(8)));
typedef __bf16 bf16x4 __attribute__((ext_vector_type(4)));
typedef float  f32x4  __attribute__((ext_vector_type(4)));
typedef float  f32x16 __attribute__((ext_vector_type(16)));
typedef unsigned u32x4 __attribute__((ext_vector_type(4)));

#define MFMA_16x16x32(A, B, C) __builtin_amdgcn_mfma_f32_16x16x32_bf16((A), (B), (C), 0, 0, 0)
#define MFMA_32x32x16(A, B, C) __builtin_amdgcn_mfma_f32_32x32x16_bf16((A), (B), (C), 0, 0, 0)

static __device__ __forceinline__ unsigned cvt_pk_bf16(float a, float b) {
  unsigned r;
  asm("v_cvt_pk_bf16_f32 %0, %1, %2" : "=v"(r) : "v"(a), "v"(b));
  return r;
}

// Stage a 128-row x 32-k bf16 tile (rows stride 512 in global) into LDS via
// async global_load_lds width=16.
static __device__ __forceinline__ void async_stage_128x32(
    const bf16* __restrict__ g0, bf16* lds, int tid) {
  const int wv = tid >> 6, ln = tid & 63;
#pragma unroll
  for (int cc = 0; cc < 2; ++cc) {
    const int c = wv + cc * 4;                       // wave-uniform chunk id
    const bf16* g = g0 + (size_t)(c * 16 + (ln >> 2)) * 512 + (ln & 3) * 8;
    __builtin_amdgcn_global_load_lds(
        (const __attribute__((address_space(1))) void*)g,
        (__attribute__((address_space(3))) void*)(lds + c * 512),
        16, 0, 0);
  }
}

// 64-row variant (one 16-row chunk per wave).
static __device__ __forceinline__ void async_stage_64x32(
    const bf16* __restrict__ g0, bf16* lds, int tid) {
  const int wv = tid >> 6, ln = tid & 63;
  const bf16* g = g0 + (size_t)(wv * 16 + (ln >> 2)) * 512 + (ln & 3) * 8;
  __builtin_amdgcn_global_load_lds(
      (const __attribute__((address_space(1))) void*)g,
      (__attribute__((address_space(3))) void*)(lds + wv * 512),
      16, 0, 0);
}

// ---------------------------------------------------------------------------
// Kernel 1: fused GroupNorm (stats + apply + transpose) and weight cvt.
// Blocks [0,256): block bg=(b,g) owns 16 channels x 1024 tokens held in
// registers (thread t: c=0..15 at n=4t..4t+3); one HBM read of x total.
// Blocks [256, 256+1024): fp32->bf16 weight conversion (float4).
__global__ __launch_bounds__(256) void gn_fused_kernel(
    const float* __restrict__ x,
    const float* __restrict__ gn_w, const float* __restrict__ gn_b,
    const float* __restrict__ qw, const float* __restrict__ pw,
    bf16* __restrict__ wq, bf16* __restrict__ wp, bf16* __restrict__ xn_t) {
  const int t = threadIdx.x;
  if (blockIdx.x >= 256) {
    const int idx = (blockIdx.x - 256) * 256 + t;    // float4 id
    if (idx < 196608) {                              // 1536*512/4
      float4 v = ((const float4*)qw)[idx];
      bf16x4 o = { (bf16)v.x, (bf16)v.y, (bf16)v.z, (bf16)v.w };
      *(bf16x4*)(&wq[idx * 4]) = o;
    }
    if (idx < 65536) {                               // 512*512/4
      float4 v = ((const float4*)pw)[idx];
      bf16x4 o = { (bf16)v.x, (bf16)v.y, (bf16)v.z, (bf16)v.w };
      *(bf16x4*)(&wp[idx * 4]) = o;
    }
    return;
  }
  const int bg = blockIdx.x;                        // 0..255
  const int b = bg >> 5, g = bg & 31;
  const int c0 = g * 16;
  const float4* p = (const float4*)(x + ((size_t)b * 512 + c0) * 1024);
  float4 v[16];
  float s = 0.f, s2 = 0.f;
#pragma unroll
  for (int i = 0; i < 16; ++i) {                     // c=i, n=4t..4t+3
    v[i] = p[t + 256 * i];
    s  += (v[i].x + v[i].y) + (v[i].z + v[i].w);
    s2 += (v[i].x * v[i].x + v[i].y * v[i].y) + (v[i].z * v[i].z + v[i].w * v[i].w);
  }
#pragma unroll
  for (int d = 1; d < 64; d <<= 1) {
    s  += __shfl_xor(s,  d);
    s2 += __shfl_xor(s2, d);
  }
  __shared__ float as[4], as2[4];
  __shared__ float scs[16], shs[16];
  if ((t & 63) == 0) { as[t >> 6] = s; as2[t >> 6] = s2; }
  __syncthreads();
  if (t < 16) {
    float S  = as[0] + as[1] + as[2] + as[3];
    float S2 = as2[0] + as2[1] + as2[2] + as2[3];
    float m  = S * (1.0f / 16384.0f);
    float rs = rsqrtf(S2 * (1.0f / 16384.0f) - m * m + 1e-5f);
    float sc = rs * gn_w[c0 + t];
    scs[t] = sc;
    shs[t] = gn_b[c0 + t] - m * sc;
  }
  __syncthreads();
  bf16* ob = xn_t + ((size_t)b * 1024 + 4 * t) * 512 + c0;
#pragma unroll
  for (int j = 0; j < 4; ++j) {                      // n = 4t + j
    bf16 tmp[16];
#pragma unroll
    for (int i = 0; i < 16; ++i) {
      float val = (j == 0) ? v[i].x : (j == 1) ? v[i].y : (j == 2) ? v[i].z : v[i].w;
      tmp[i] = (bf16)(val * scs[i] + shs[i]);
    }
    *(bf16x8*)(ob + (size_t)j * 512)     = *(bf16x8*)(tmp);
    *(bf16x8*)(ob + (size_t)j * 512 + 8) = *(bf16x8*)(tmp + 8);
  }
}

// ---------------------------------------------------------------------------
// Kernel 2: QKV GEMM, single-barrier dbuf K-loop (BK=32, 16 iters).
// Q rows (o<512) pre-scaled by 0.125*log2(e). Q,K -> qkv_t token-major.
// V blocks swap MFMA operands (D^T) so the v_t[b][h][d][n] store is
// vectorized bf16x4 along n.
__global__ __launch_bounds__(256) void qkv_gemm_kernel(
    const bf16* __restrict__ W, const bf16* __restrict__ xn_t,
    const float* __restrict__ qkv_b, bf16* __restrict__ qkv_t,
    bf16* __restrict__ v_t) {
  const int n0 = blockIdx.x * 128;
  const int o0 = blockIdx.y * 128;
  const int b  = blockIdx.z;
  __shared__ bf16 As[2][128 * 32];
  __shared__ bf16 Bs[2][128 * 32];
  const int tid = threadIdx.x, ln = tid & 63, wv = tid >> 6;
  const int mw = (wv >> 1) * 64, nw = (wv & 1) * 64;
  const int l15 = ln & 15, lg = ln >> 4;
  const bool isV = (o0 >= 1024);
  const bf16* gA = W + (size_t)o0 * 512;
  const bf16* gB = xn_t + ((size_t)b * 1024 + n0) * 512;
  f32x4 acc[4][4] = {};
  async_stage_128x32(gA, As[0], tid);
  async_stage_128x32(gB, Bs[0], tid);
  for (int it = 0; it < 16; ++it) {
    __syncthreads();                                 // publish buf[cur]
    const int cur = it & 1, nxt = cur ^ 1;
    if (it < 15) {                                   // prefetch overlaps compute
      async_stage_128x32(gA + (it + 1) * 32, As[nxt], tid);
      async_stage_128x32(gB + (it + 1) * 32, Bs[nxt], tid);
    }
    bf16x8 af[4], bfr[4];
#pragma unroll
    for (int mi = 0; mi < 4; ++mi)
      af[mi] = *(const bf16x8*)(&As[cur][(mw + mi * 16 + l15) * 32 + lg * 8]);
#pragma unroll
    for (int nj = 0; nj < 4; ++nj)
      bfr[nj] = *(const bf16x8*)(&Bs[cur][(nw + nj * 16 + l15) * 32 + lg * 8]);
    if (!isV) {
#pragma unroll
      for (int mi = 0; mi < 4; ++mi)
#pragma unroll
        for (int nj = 0; nj < 4; ++nj)
          acc[mi][nj] = MFMA_16x16x32(af[mi], bfr[nj], acc[mi][nj]);
    } else {                                         // swapped: acc = D^T
#pragma unroll
      for (int mi = 0; mi < 4; ++mi)
#pragma unroll
        for (int nj = 0; nj < 4; ++nj)
          acc[mi][nj] = MFMA_16x16x32(bfr[nj], af[mi], acc[mi][nj]);
    }
  }
  if (!isV) {
    const float qs = (o0 < 512) ? 0.125f * 1.44269504089f : 1.0f;
#pragma unroll
    for (int mi = 0; mi < 4; ++mi) {
      const int o = o0 + mw + mi * 16 + lg * 4;
      const float b0 = qkv_b[o], b1 = qkv_b[o + 1], b2 = qkv_b[o + 2], b3 = qkv_b[o + 3];
#pragma unroll
      for (int nj = 0; nj < 4; ++nj) {
        const int n = n0 + nw + nj * 16 + l15;
        f32x4 v = acc[mi][nj];
        bf16x4 st = { (bf16)((v.x + b0) * qs), (bf16)((v.y + b1) * qs),
                      (bf16)((v.z + b2) * qs), (bf16)((v.w + b3) * qs) };
        *(bf16x4*)(&qkv_t[((size_t)b * 1024 + n) * 1536 + o]) = st;
      }
    }
  } else {
    // swapped C-layout: lane holds D[n = nw+nj*16+lg*4+r][o = mw+mi*16+l15]
#pragma unroll
    for (int mi = 0; mi < 4; ++mi) {
      const int o  = o0 + mw + mi * 16 + l15;
      const int hd = o - 1024;                       // h*64 + d
      const float bias = qkv_b[o];
#pragma unroll
      for (int nj = 0; nj < 4; ++nj) {
        const int n = n0 + nw + nj * 16 + lg * 4;
        f32x4 v = acc[mi][nj];
        bf16x4 st = { (bf16)(v.x + bias), (bf16)(v.y + bias),
                      (bf16)(v.z + bias), (bf16)(v.w + bias) };
        *(bf16x4*)(&v_t[((size_t)b * 512 + hd) * 1024 + n]) = st;
      }
    }
  }
}

// ---------------------------------------------------------------------------
// Kernel 3: fused attention, 32x32x16 MFMA, in-register softmax P.
// 4 waves/block; wave w owns q-subtile qb = qt*128 + w*32 and sweeps ALL
// 16 kv-tiles. Swapped QK^T (mfma(K,Q)) gives S^T (col=q=lane&31,
// row=kv=(r&3)+8*(r>>2)+4*(lane>>5)); exp2 in regs; P->B-frag via
// v_cvt_pk_bf16_f32 + v_permlane32_swap_b32. K/V double-buffered in LDS
// (36864 B total), one barrier/tile, reg-prefetch issued right after the
// barrier (T14). No split-K: epilogue is 8 direct bf16x4 stores.
__global__ __launch_bounds__(256, 2) void attn_kernel(
    const bf16* __restrict__ qkv_t, const bf16* __restrict__ v_t,
    bf16* __restrict__ at_t) {
  const int qt = blockIdx.y;                        // 0..7 (128 q each)
  const int b  = blockIdx.x >> 3;
  const int h  = blockIdx.x & 7;
  __shared__ __align__(16) char smem[36864];        // 2 bufs x (K 64x72 + V 64x72)
  const int tid = threadIdx.x, wv = tid >> 6;
  const int ln = tid & 63;
  const int l31 = ln & 31, hi = ln >> 5;
  const bf16* hq  = qkv_t + (size_t)b * 1024 * 1536 + h * 64;
  const bf16* hk  = hq + 512;
  const bf16* vtb = v_t + (size_t)(b * 8 + h) * 64 * 1024;

  const int qb = qt * 128 + wv * 32;
  // Q B-fragments: lane holds q=l31, d = ks*16 + hi*8 + j
  bf16x8 qf[4];
#pragma unroll
  for (int ks = 0; ks < 4; ++ks)
    qf[ks] = *(const bf16x8*)(hq + (size_t)(qb + l31) * 1536 + ks * 16 + hi * 8);

  f32x16 oacc[2] = {};                              // O^T[d-tile][q]
  float lst = 0.f;

  // staging geometry: 256 threads, 2 row-passes of 32 rows; 8 threads/row.
  const int srow = tid >> 3;                        // 0..31
  const int scol = (tid & 7) * 8;                   // 0..56

  // prologue: stage kv-tile 0 into buf 0
  bf16x8 k0, k1, v0, v1;
  {
    const bf16* gk = hk + (size_t)srow * 1536 + scol;
    const bf16* gv = vtb + (size_t)srow * 1024 + scol;
    k0 = *(const bf16x8*)(gk);
    k1 = *(const bf16x8*)(gk + 32 * 1536);
    v0 = *(const bf16x8*)(gv);
    v1 = *(const bf16x8*)(gv + 32 * 1024);
    bf16* Kt = (bf16*)(smem);
    bf16* Vt = Kt + 64 * 72;
    *(bf16x8*)(&Kt[srow * 72 + scol])        = k0;
    *(bf16x8*)(&Kt[(srow + 32) * 72 + scol]) = k1;
    *(bf16x8*)(&Vt[srow * 72 + scol])        = v0;
    *(bf16x8*)(&Vt[(srow + 32) * 72 + scol]) = v1;
  }

  for (int i = 0; i < 16; ++i) {
    __syncthreads();                                 // publish buf[i&1]
    if (i < 15) {                                    // issue prefetch NOW,
      const int kt = i + 1;                          // stored after compute
      const bf16* gk = hk  + (size_t)(kt * 64 + srow) * 1536 + scol;
      const bf16* gv = vtb + (size_t)srow * 1024 + kt * 64 + scol;
      k0 = *(const bf16x8*)(gk);
      k1 = *(const bf16x8*)(gk + 32 * 1536);
      v0 = *(const bf16x8*)(gv);
      v1 = *(const bf16x8*)(gv + 32 * 1024);
    }
    const bf16* Kt = (const bf16*)(smem + (i & 1) * 18432);
    const bf16* Vt = Kt + 64 * 72;

#pragma unroll
    for (int kk = 0; kk < 2; ++kk) {
      const int kvb = kk * 32;
      f32x16 st = {};
      __builtin_amdgcn_s_setprio(1);
#pragma unroll
      for (int ks = 0; ks < 4; ++ks) {
        bf16x8 kf = *(const bf16x8*)(&Kt[(kvb + l31) * 72 + ks * 16 + hi * 8]);
        st = MFMA_32x32x16(kf, qf[ks], st);
      }
      __builtin_amdgcn_s_setprio(0);
#pragma unroll
      for (int r = 0; r < 16; ++r) st[r] = exp2f(st[r]);
      lst += ((st[0] + st[1]) + (st[2] + st[3])) + ((st[4] + st[5]) + (st[6] + st[7]))
           + ((st[8] + st[9]) + (st[10] + st[11])) + ((st[12] + st[13]) + (st[14] + st[15]));
#pragma unroll
      for (int t = 0; t < 2; ++t) {
        // own regs hold kv rows crow(r,hi); swap lane-halves to build B-frag
        // (lane needs kv = t*16 + hi*8 + j). After swap: {x0,x1,y0,y1} are
        // the 4 B-frag words in order.
        unsigned x0 = cvt_pk_bf16(st[t * 8 + 0], st[t * 8 + 1]);
        unsigned x1 = cvt_pk_bf16(st[t * 8 + 2], st[t * 8 + 3]);
        unsigned y0 = cvt_pk_bf16(st[t * 8 + 4], st[t * 8 + 5]);
        unsigned y1 = cvt_pk_bf16(st[t * 8 + 6], st[t * 8 + 7]);
        asm("v_permlane32_swap_b32 %0, %1" : "+v"(x0), "+v"(y0));
        asm("v_permlane32_swap_b32 %0, %1" : "+v"(x1), "+v"(y1));
        u32x4 pu = { x0, x1, y0, y1 };
        bf16x8 pb = __builtin_bit_cast(bf16x8, pu);
        __builtin_amdgcn_s_setprio(1);
#pragma unroll
        for (int dt = 0; dt < 2; ++dt) {
          bf16x8 vf = *(const bf16x8*)(&Vt[(dt * 32 + l31) * 72 + kvb + t * 16 + hi * 8]);
          oacc[dt] = MFMA_32x32x16(vf, pb, oacc[dt]);
        }
        __builtin_amdgcn_s_setprio(0);
      }
    }

    if (i < 15) {                                    // store prefetched tile
      bf16* Ktn = (bf16*)(smem + ((i + 1) & 1) * 18432);
      bf16* Vtn = Ktn + 64 * 72;
      *(bf16x8*)(&Ktn[srow * 72 + scol])        = k0;
      *(bf16x8*)(&Ktn[(srow + 32) * 72 + scol]) = k1;
      *(bf16x8*)(&Vtn[srow * 72 + scol])        = v0;
      *(bf16x8*)(&Vtn[(srow + 32) * 72 + scol]) = v1;
    }
  }

  // lanes l / l+32 hold complementary kv rows for the same q
  const float lf = lst + __shfl_xor(lst, 32);
  const float inv = 1.0f / lf;
  const int q = qb + l31;
  bf16* ob = at_t + ((size_t)b * 1024 + q) * 512 + h * 64;
#pragma unroll
  for (int dt = 0; dt < 2; ++dt)
#pragma unroll
    for (int rr = 0; rr < 4; ++rr) {
      bf16x4 ov = { (bf16)(oacc[dt][rr * 4 + 0] * inv),
                    (bf16)(oacc[dt][rr * 4 + 1] * inv),
                    (bf16)(oacc[dt][rr * 4 + 2] * inv),
                    (bf16)(oacc[dt][rr * 4 + 3] * inv) };
      *(bf16x4*)(ob + dt * 32 + rr * 8 + hi * 4) = ov;
    }
}

// ---------------------------------------------------------------------------
// Kernel 4: proj GEMM + bias + residual. BM=64, single-barrier dbuf (BK=32).
__global__ __launch_bounds__(256) void proj_gemm_kernel(
    const bf16* __restrict__ at_t, const bf16* __restrict__ wp,
    const float* __restrict__ proj_b, const float* __restrict__ x,
    float* __restrict__ out) {
  const int i0 = blockIdx.x * 64;                   // token tile (64)
  const int c0 = blockIdx.y * 128;                  // out-channel tile (128)
  const int b  = blockIdx.z;
  __shared__ bf16 As[2][64 * 32];
  __shared__ bf16 Bs[2][128 * 32];
  const int tid = threadIdx.x, ln = tid & 63, wv = tid >> 6;
  const int mw = (wv >> 1) * 32, nw = (wv & 1) * 64;
  const int l15 = ln & 15, lg = ln >> 4;
  const bf16* gA = at_t + ((size_t)b * 1024 + i0) * 512;
  const bf16* gB = wp + (size_t)c0 * 512;
  f32x4 acc[2][4] = {};
  async_stage_64x32(gA, As[0], tid);
  async_stage_128x32(gB, Bs[0], tid);
  for (int it = 0; it < 16; ++it) {
    __syncthreads();
    const int cur = it & 1, nxt = cur ^ 1;
    if (it < 15) {
      async_stage_64x32(gA + (it + 1) * 32, As[nxt], tid);
      async_stage_128x32(gB + (it + 1) * 32, Bs[nxt], tid);
    }
    bf16x8 af[2], bfr[4];
#pragma unroll
    for (int mi = 0; mi < 2; ++mi)
      af[mi] = *(const bf16x8*)(&As[cur][(mw + mi * 16 + l15) * 32 + lg * 8]);
#pragma unroll
    for (int nj = 0; nj < 4; ++nj)
      bfr[nj] = *(const bf16x8*)(&Bs[cur][(nw + nj * 16 + l15) * 32 + lg * 8]);
#pragma unroll
    for (int mi = 0; mi < 2; ++mi)
#pragma unroll
      for (int nj = 0; nj < 4; ++nj)
        acc[mi][nj] = MFMA_16x16x32(af[mi], bfr[nj], acc[mi][nj]);
  }
#pragma unroll
  for (int mi = 0; mi < 2; ++mi) {
    const int i = i0 + mw + mi * 16 + lg * 4;
#pragma unroll
    for (int nj = 0; nj < 4; ++nj) {
      const int c = c0 + nw + nj * 16 + l15;
      const float bias = proj_b[c];
      const size_t off = ((size_t)b * 512 + c) * 1024 + i;
      const float4 res = *(const float4*)(x + off);
      f32x4 v = acc[mi][nj];
      float4 ov;
      ov.x = v.x + bias + res.x;
      ov.y = v.y + bias + res.y;
      ov.z = v.z + bias + res.z;
      ov.w = v.w + bias + res.w;
      *(float4*)(out + off) = ov;
    }
  }
}

// ---------------------------------------------------------------------------
extern "C" void kernel_launch(void* const* d_in, const int* in_sizes, int n_in,
                              void* d_out, int out_size, void* d_ws, size_t ws_size,
                              hipStream_t stream) {
  (void)in_sizes; (void)n_in; (void)out_size; (void)ws_size;
  const float* x      = (const float*)d_in[0];
  const float* gn_w   = (const float*)d_in[1];
  const float* gn_b   = (const float*)d_in[2];
  const float* qkv_w  = (const float*)d_in[3];
  const float* qkv_b  = (const float*)d_in[4];
  const float* proj_w = (const float*)d_in[5];
  const float* proj_b = (const float*)d_in[6];
  float* out = (float*)d_out;

  // workspace layout (~100 MB)
  char* ws = (char*)d_ws;
  bf16* wq    = (bf16*)ws;                          // [1536][512]
  bf16* wp    = wq + (size_t)1536 * 512;            // [512][512]
  bf16* xn_t  = wp + (size_t)512 * 512;             // [8][1024][512]
  bf16* qkv_t = xn_t + (size_t)8 * 1024 * 512;      // [8][1024][1536] (Q,K only)
  bf16* at_t  = qkv_t + (size_t)8 * 1024 * 1536;    // [8][1024][512]
  bf16* v_t   = at_t + (size_t)8 * 1024 * 512;      // [8][8][64][1024]

  hipLaunchKernelGGL(gn_fused_kernel, dim3(1280),     dim3(256), 0, stream,
                     x, gn_w, gn_b, qkv_w, proj_w, wq, wp, xn_t);
  hipLaunchKernelGGL(qkv_gemm_kernel, dim3(8, 12, 8), dim3(256), 0, stream,
                     wq, xn_t, qkv_b, qkv_t, v_t);
  hipLaunchKernelGGL(attn_kernel,     dim3(64, 8),    dim3(256), 0, stream,
                     qkv_t, v_t, at_t);
  hipLaunchKernelGGL(proj_gemm_kernel,dim3(16, 4, 8), dim3(256), 0, stream,
                     at_t, wp, proj_b, x, out);
}

// Round 4
// 156.727 us; speedup vs baseline: 1.0028x; 1.0028x over previous
//
#include <hip/hip_runtime.h>

// ---------------------------------------------------------------------------
// AttentionBlock: GroupNorm -> QKV 1x1 conv -> MHA (8 heads, d=64, N=1024)
//               -> proj 1x1 conv -> +residual
// Shapes: B=8, C=512, H=W=32 (N=1024), groups=32, heads=8, hd=64. fp32 I/O.
// R14->R15: attn = hybrid of R12 (measured-best 154.2) and R13/R14 (passed,
// but 157.2). Keep R12's 8-wave dual-kv-split skeleton -> 512 thr, 2
// blocks/CU, 16 waves/CU (R14's 4-wave variant halved occupancy and
// regressed; attn is stall-bound so occupancy wins). Swap the per-wave
// compute to R13's verified 32x32x16 MFMA core (4060 vs 3378 FLOP/cyc,
// -17% matrix-pipe cycles) with in-register P (cvt_pk_bf16+permlane32_swap)
// and the 1-barrier/iter dbuf K/V staging (R12 ran 2 barriers/iter).
// Split-combine epilogue via LDS f32 exchange as in R12.
// ---------------------------------------------------------------------------

typedef __bf16 bf16;
typedef __bf16 bf16x8 __attribute__((ext_vector_type(8)));
typedef __bf16 bf16x4 __attribute__((ext_vector_type(4)));
typedef float  f32x4  __attribute__((ext_vector_type(4)));
typedef float  f32x16 __attribute__((ext_vector_type(16)));
typedef unsigned u32x4 __attribute__((ext_vector_type(4)));

#define MFMA_16x16x32(A, B, C) __builtin_amdgcn_mfma_f32_16x16x32_bf16((A), (B), (C), 0, 0, 0)
#define MFMA_32x32x16(A, B, C) __builtin_amdgcn_mfma_f32_32x32x16_bf16((A), (B), (C), 0, 0, 0)

static __device__ __forceinline__ unsigned cvt_pk_bf16(float a, float b) {
  unsigned r;
  asm("v_cvt_pk_bf16_f32 %0, %1, %2" : "=v"(r) : "v"(a), "v"(b));
  return r;
}

// Stage a 128-row x 32-k bf16 tile (rows stride 512 in global) into LDS via
// async global_load_lds width=16.
static __device__ __forceinline__ void async_stage_128x32(
    const bf16* __restrict__ g0, bf16* lds, int tid) {
  const int wv = tid >> 6, ln = tid & 63;
#pragma unroll
  for (int cc = 0; cc < 2; ++cc) {
    const int c = wv + cc * 4;                       // wave-uniform chunk id
    const bf16* g = g0 + (size_t)(c * 16 + (ln >> 2)) * 512 + (ln & 3) * 8;
    __builtin_amdgcn_global_load_lds(
        (const __attribute__((address_space(1))) void*)g,
        (__attribute__((address_space(3))) void*)(lds + c * 512),
        16, 0, 0);
  }
}

// 64-row variant (one 16-row chunk per wave).
static __device__ __forceinline__ void async_stage_64x32(
    const bf16* __restrict__ g0, bf16* lds, int tid) {
  const int wv = tid >> 6, ln = tid & 63;
  const bf16* g = g0 + (size_t)(wv * 16 + (ln >> 2)) * 512 + (ln & 3) * 8;
  __builtin_amdgcn_global_load_lds(
      (const __attribute__((address_space(1))) void*)g,
      (__attribute__((address_space(3))) void*)(lds + wv * 512),
      16, 0, 0);
}

// ---------------------------------------------------------------------------
// Kernel 1: fused GroupNorm (stats + apply + transpose) and weight cvt.
// Blocks [0,256): block bg=(b,g) owns 16 channels x 1024 tokens held in
// registers (thread t: c=0..15 at n=4t..4t+3); one HBM read of x total.
// Blocks [256, 256+1024): fp32->bf16 weight conversion (float4).
__global__ __launch_bounds__(256) void gn_fused_kernel(
    const float* __restrict__ x,
    const float* __restrict__ gn_w, const float* __restrict__ gn_b,
    const float* __restrict__ qw, const float* __restrict__ pw,
    bf16* __restrict__ wq, bf16* __restrict__ wp, bf16* __restrict__ xn_t) {
  const int t = threadIdx.x;
  if (blockIdx.x >= 256) {
    const int idx = (blockIdx.x - 256) * 256 + t;    // float4 id
    if (idx < 196608) {                              // 1536*512/4
      float4 v = ((const float4*)qw)[idx];
      bf16x4 o = { (bf16)v.x, (bf16)v.y, (bf16)v.z, (bf16)v.w };
      *(bf16x4*)(&wq[idx * 4]) = o;
    }
    if (idx < 65536) {                               // 512*512/4
      float4 v = ((const float4*)pw)[idx];
      bf16x4 o = { (bf16)v.x, (bf16)v.y, (bf16)v.z, (bf16)v.w };
      *(bf16x4*)(&wp[idx * 4]) = o;
    }
    return;
  }
  const int bg = blockIdx.x;                        // 0..255
  const int b = bg >> 5, g = bg & 31;
  const int c0 = g * 16;
  const float4* p = (const float4*)(x + ((size_t)b * 512 + c0) * 1024);
  float4 v[16];
  float s = 0.f, s2 = 0.f;
#pragma unroll
  for (int i = 0; i < 16; ++i) {                     // c=i, n=4t..4t+3
    v[i] = p[t + 256 * i];
    s  += (v[i].x + v[i].y) + (v[i].z + v[i].w);
    s2 += (v[i].x * v[i].x + v[i].y * v[i].y) + (v[i].z * v[i].z + v[i].w * v[i].w);
  }
#pragma unroll
  for (int d = 1; d < 64; d <<= 1) {
    s  += __shfl_xor(s,  d);
    s2 += __shfl_xor(s2, d);
  }
  __shared__ float as[4], as2[4];
  __shared__ float scs[16], shs[16];
  if ((t & 63) == 0) { as[t >> 6] = s; as2[t >> 6] = s2; }
  __syncthreads();
  if (t < 16) {
    float S  = as[0] + as[1] + as[2] + as[3];
    float S2 = as2[0] + as2[1] + as2[2] + as2[3];
    float m  = S * (1.0f / 16384.0f);
    float rs = rsqrtf(S2 * (1.0f / 16384.0f) - m * m + 1e-5f);
    float sc = rs * gn_w[c0 + t];
    scs[t] = sc;
    shs[t] = gn_b[c0 + t] - m * sc;
  }
  __syncthreads();
  bf16* ob = xn_t + ((size_t)b * 1024 + 4 * t) * 512 + c0;
#pragma unroll
  for (int j = 0; j < 4; ++j) {                      // n = 4t + j
    bf16 tmp[16];
#pragma unroll
    for (int i = 0; i < 16; ++i) {
      float val = (j == 0) ? v[i].x : (j == 1) ? v[i].y : (j == 2) ? v[i].z : v[i].w;
      tmp[i] = (bf16)(val * scs[i] + shs[i]);
    }
    *(bf16x8*)(ob + (size_t)j * 512)     = *(bf16x8*)(tmp);
    *(bf16x8*)(ob + (size_t)j * 512 + 8) = *(bf16x8*)(tmp + 8);
  }
}

// ---------------------------------------------------------------------------
// Kernel 2: QKV GEMM, single-barrier dbuf K-loop (BK=32, 16 iters).
// Q rows (o<512) pre-scaled by 0.125*log2(e). Q,K -> qkv_t token-major.
// V blocks swap MFMA operands (D^T) so the v_t[b][h][d][n] store is
// vectorized bf16x4 along n.
__global__ __launch_bounds__(256) void qkv_gemm_kernel(
    const bf16* __restrict__ W, const bf16* __restrict__ xn_t,
    const float* __restrict__ qkv_b, bf16* __restrict__ qkv_t,
    bf16* __restrict__ v_t) {
  const int n0 = blockIdx.x * 128;
  const int o0 = blockIdx.y * 128;
  const int b  = blockIdx.z;
  __shared__ bf16 As[2][128 * 32];
  __shared__ bf16 Bs[2][128 * 32];
  const int tid = threadIdx.x, ln = tid & 63, wv = tid >> 6;
  const int mw = (wv >> 1) * 64, nw = (wv & 1) * 64;
  const int l15 = ln & 15, lg = ln >> 4;
  const bool isV = (o0 >= 1024);
  const bf16* gA = W + (size_t)o0 * 512;
  const bf16* gB = xn_t + ((size_t)b * 1024 + n0) * 512;
  f32x4 acc[4][4] = {};
  async_stage_128x32(gA, As[0], tid);
  async_stage_128x32(gB, Bs[0], tid);
  for (int it = 0; it < 16; ++it) {
    __syncthreads();                                 // publish buf[cur]
    const int cur = it & 1, nxt = cur ^ 1;
    if (it < 15) {                                   // prefetch overlaps compute
      async_stage_128x32(gA + (it + 1) * 32, As[nxt], tid);
      async_stage_128x32(gB + (it + 1) * 32, Bs[nxt], tid);
    }
    bf16x8 af[4], bfr[4];
#pragma unroll
    for (int mi = 0; mi < 4; ++mi)
      af[mi] = *(const bf16x8*)(&As[cur][(mw + mi * 16 + l15) * 32 + lg * 8]);
#pragma unroll
    for (int nj = 0; nj < 4; ++nj)
      bfr[nj] = *(const bf16x8*)(&Bs[cur][(nw + nj * 16 + l15) * 32 + lg * 8]);
    if (!isV) {
#pragma unroll
      for (int mi = 0; mi < 4; ++mi)
#pragma unroll
        for (int nj = 0; nj < 4; ++nj)
          acc[mi][nj] = MFMA_16x16x32(af[mi], bfr[nj], acc[mi][nj]);
    } else {                                         // swapped: acc = D^T
#pragma unroll
      for (int mi = 0; mi < 4; ++mi)
#pragma unroll
        for (int nj = 0; nj < 4; ++nj)
          acc[mi][nj] = MFMA_16x16x32(bfr[nj], af[mi], acc[mi][nj]);
    }
  }
  if (!isV) {
    const float qs = (o0 < 512) ? 0.125f * 1.44269504089f : 1.0f;
#pragma unroll
    for (int mi = 0; mi < 4; ++mi) {
      const int o = o0 + mw + mi * 16 + lg * 4;
      const float b0 = qkv_b[o], b1 = qkv_b[o + 1], b2 = qkv_b[o + 2], b3 = qkv_b[o + 3];
#pragma unroll
      for (int nj = 0; nj < 4; ++nj) {
        const int n = n0 + nw + nj * 16 + l15;
        f32x4 v = acc[mi][nj];
        bf16x4 st = { (bf16)((v.x + b0) * qs), (bf16)((v.y + b1) * qs),
                      (bf16)((v.z + b2) * qs), (bf16)((v.w + b3) * qs) };
        *(bf16x4*)(&qkv_t[((size_t)b * 1024 + n) * 1536 + o]) = st;
      }
    }
  } else {
    // swapped C-layout: lane holds D[n = nw+nj*16+lg*4+r][o = mw+mi*16+l15]
#pragma unroll
    for (int mi = 0; mi < 4; ++mi) {
      const int o  = o0 + mw + mi * 16 + l15;
      const int hd = o - 1024;                       // h*64 + d
      const float bias = qkv_b[o];
#pragma unroll
      for (int nj = 0; nj < 4; ++nj) {
        const int n = n0 + nw + nj * 16 + lg * 4;
        f32x4 v = acc[mi][nj];
        bf16x4 st = { (bf16)(v.x + bias), (bf16)(v.y + bias),
                      (bf16)(v.z + bias), (bf16)(v.w + bias) };
        *(bf16x4*)(&v_t[((size_t)b * 512 + hd) * 1024 + n]) = st;
      }
    }
  }
}

// ---------------------------------------------------------------------------
// Kernel 3: fused attention. 8 waves = 2 kv-halves x 4 q-subtiles(32 q).
// half h sweeps kv tiles [h*8, h*8+8). 32x32x16 MFMA, swapped QK^T
// (mfma(K,Q) -> S^T col=q=lane&31, row=kv=(r&3)+8*(r>>2)+4*(lane>>5));
// exp2 in regs; P->B-frag via v_cvt_pk_bf16_f32 + v_permlane32_swap_b32
// (no P LDS round trip). K/V double-buffered (2 x 36864 B), ONE barrier
// per tile, reg-prefetch issued right after the barrier (T14). Halves
// combine O/l through a f32 LDS exchange at the end.
__global__ __launch_bounds__(512, 4) void attn_kernel(
    const bf16* __restrict__ qkv_t, const bf16* __restrict__ v_t,
    bf16* __restrict__ at_t) {
  const int qt = blockIdx.y;                        // 0..7 (128 q each)
  const int b  = blockIdx.x >> 3;
  const int h  = blockIdx.x & 7;
  __shared__ __align__(16) char smem[73728];        // 2 bufs x 2 halves x (K+V 64x72)
  const int tid = threadIdx.x, ln = tid & 63, wv = tid >> 6;
  const int half = wv >> 2, w4 = wv & 3;
  const int l31 = ln & 31, hi = ln >> 5;
  const bf16* hq  = qkv_t + (size_t)b * 1024 * 1536 + h * 64;
  const bf16* hk  = hq + 512;
  const bf16* vtb = v_t + (size_t)(b * 8 + h) * 64 * 1024;

  const int qb = qt * 128 + w4 * 32;
  // Q B-fragments: lane holds q=l31, d = ks*16 + hi*8 + j
  bf16x8 qf[4];
#pragma unroll
  for (int ks = 0; ks < 4; ++ks)
    qf[ks] = *(const bf16x8*)(hq + (size_t)(qb + l31) * 1536 + ks * 16 + hi * 8);

  f32x16 oacc[2] = {};                              // O^T[d-tile][q]
  float lst = 0.f;

  // staging: 256 threads per half stage that half's 64x64 K and V tiles.
  const int t256 = tid & 255;
  const int srow = t256 >> 2, scg = (t256 & 3) * 16;
  const int kt0 = half * 8;

  bf16x8 k0r, k1r, v0r, v1r;
  {                                                  // prologue: tile kt0 -> buf0
    const bf16* gk = hk  + (size_t)(kt0 * 64 + srow) * 1536 + scg;
    const bf16* gv = vtb + (size_t)srow * 1024 + kt0 * 64 + scg;
    k0r = *(const bf16x8*)(gk);
    k1r = *(const bf16x8*)(gk + 8);
    v0r = *(const bf16x8*)(gv);
    v1r = *(const bf16x8*)(gv + 8);
    bf16* Kt = (bf16*)(smem + half * 18432);
    bf16* Vt = Kt + 64 * 72;
    *(bf16x8*)(&Kt[srow * 72 + scg])     = k0r;
    *(bf16x8*)(&Kt[srow * 72 + scg + 8]) = k1r;
    *(bf16x8*)(&Vt[srow * 72 + scg])     = v0r;
    *(bf16x8*)(&Vt[srow * 72 + scg + 8]) = v1r;
  }

  for (int i = 0; i < 8; ++i) {
    __syncthreads();                                 // publish buf[i&1]
    if (i < 7) {                                     // issue prefetch NOW,
      const int kt = kt0 + i + 1;                    // stored after compute
      const bf16* gk = hk  + (size_t)(kt * 64 + srow) * 1536 + scg;
      const bf16* gv = vtb + (size_t)srow * 1024 + kt * 64 + scg;
      k0r = *(const bf16x8*)(gk);
      k1r = *(const bf16x8*)(gk + 8);
      v0r = *(const bf16x8*)(gv);
      v1r = *(const bf16x8*)(gv + 8);
    }
    const bf16* Kt = (const bf16*)(smem + (i & 1) * 36864 + half * 18432);
    const bf16* Vt = Kt + 64 * 72;

#pragma unroll
    for (int kk = 0; kk < 2; ++kk) {
      const int kvb = kk * 32;
      f32x16 st = {};
      __builtin_amdgcn_s_setprio(1);
#pragma unroll
      for (int ks = 0; ks < 4; ++ks) {
        bf16x8 kf = *(const bf16x8*)(&Kt[(kvb + l31) * 72 + ks * 16 + hi * 8]);
        st = MFMA_32x32x16(kf, qf[ks], st);
      }
      __builtin_amdgcn_s_setprio(0);
#pragma unroll
      for (int r = 0; r < 16; ++r) st[r] = exp2f(st[r]);
      lst += ((st[0] + st[1]) + (st[2] + st[3])) + ((st[4] + st[5]) + (st[6] + st[7]))
           + ((st[8] + st[9]) + (st[10] + st[11])) + ((st[12] + st[13]) + (st[14] + st[15]));
#pragma unroll
      for (int t = 0; t < 2; ++t) {
        // own regs hold kv rows crow(r,hi); swap lane-halves to build B-frag
        // (lane needs kv = t*16 + hi*8 + j). After swap: {x0,x1,y0,y1} are
        // the 4 B-frag words in order.
        unsigned x0 = cvt_pk_bf16(st[t * 8 + 0], st[t * 8 + 1]);
        unsigned x1 = cvt_pk_bf16(st[t * 8 + 2], st[t * 8 + 3]);
        unsigned y0 = cvt_pk_bf16(st[t * 8 + 4], st[t * 8 + 5]);
        unsigned y1 = cvt_pk_bf16(st[t * 8 + 6], st[t * 8 + 7]);
        asm("v_permlane32_swap_b32 %0, %1" : "+v"(x0), "+v"(y0));
        asm("v_permlane32_swap_b32 %0, %1" : "+v"(x1), "+v"(y1));
        u32x4 pu = { x0, x1, y0, y1 };
        bf16x8 pb = __builtin_bit_cast(bf16x8, pu);
        __builtin_amdgcn_s_setprio(1);
#pragma unroll
        for (int dt = 0; dt < 2; ++dt) {
          bf16x8 vf = *(const bf16x8*)(&Vt[(dt * 32 + l31) * 72 + kvb + t * 16 + hi * 8]);
          oacc[dt] = MFMA_32x32x16(vf, pb, oacc[dt]);
        }
        __builtin_amdgcn_s_setprio(0);
      }
    }

    if (i < 7) {                                     // store prefetched tile
      bf16* Ktn = (bf16*)(smem + ((i + 1) & 1) * 36864 + half * 18432);
      bf16* Vtn = Ktn + 64 * 72;
      *(bf16x8*)(&Ktn[srow * 72 + scg])     = k0r;
      *(bf16x8*)(&Ktn[srow * 72 + scg + 8]) = k1r;
      *(bf16x8*)(&Vtn[srow * 72 + scg])     = v0r;
      *(bf16x8*)(&Vtn[srow * 72 + scg + 8]) = v1r;
    }
  }

  // lanes l / l+32 hold complementary kv rows for the same q (within half)
  const float lf = lst + __shfl_xor(lst, 32);

  // combine halves: half 1 publishes O^T + l via LDS; half 0 merges+stores.
  float* MB  = (float*)smem;                        // [w4][32 q][68 d-stride]
  float* MLb = (float*)(smem + 34816);              // [w4][32]
  __syncthreads();
  if (half == 1) {
    float* mb = MB + w4 * (32 * 68);
#pragma unroll
    for (int dt = 0; dt < 2; ++dt)
#pragma unroll
      for (int rr = 0; rr < 4; ++rr) {
        f32x4 v = { oacc[dt][rr * 4 + 0], oacc[dt][rr * 4 + 1],
                    oacc[dt][rr * 4 + 2], oacc[dt][rr * 4 + 3] };
        *(f32x4*)(mb + l31 * 68 + dt * 32 + rr * 8 + hi * 4) = v;
      }
    if (hi == 0) MLb[w4 * 32 + l31] = lf;
  }
  __syncthreads();
  if (half == 0) {
    const float* mb = MB + w4 * (32 * 68);
    const float inv = 1.0f / (lf + MLb[w4 * 32 + l31]);
    const int q = qb + l31;
    bf16* ob = at_t + ((size_t)b * 1024 + q) * 512 + h * 64;
#pragma unroll
    for (int dt = 0; dt < 2; ++dt)
#pragma unroll
      for (int rr = 0; rr < 4; ++rr) {
        f32x4 obv = *(const f32x4*)(mb + l31 * 68 + dt * 32 + rr * 8 + hi * 4);
        bf16x4 ov = { (bf16)((oacc[dt][rr * 4 + 0] + obv[0]) * inv),
                      (bf16)((oacc[dt][rr * 4 + 1] + obv[1]) * inv),
                      (bf16)((oacc[dt][rr * 4 + 2] + obv[2]) * inv),
                      (bf16)((oacc[dt][rr * 4 + 3] + obv[3]) * inv) };
        *(bf16x4*)(ob + dt * 32 + rr * 8 + hi * 4) = ov;
      }
  }
}

// ---------------------------------------------------------------------------
// Kernel 4: proj GEMM + bias + residual. BM=64, single-barrier dbuf (BK=32).
__global__ __launch_bounds__(256) void proj_gemm_kernel(
    const bf16* __restrict__ at_t, const bf16* __restrict__ wp,
    const float* __restrict__ proj_b, const float* __restrict__ x,
    float* __restrict__ out) {
  const int i0 = blockIdx.x * 64;                   // token tile (64)
  const int c0 = blockIdx.y * 128;                  // out-channel tile (128)
  const int b  = blockIdx.z;
  __shared__ bf16 As[2][64 * 32];
  __shared__ bf16 Bs[2][128 * 32];
  const int tid = threadIdx.x, ln = tid & 63, wv = tid >> 6;
  const int mw = (wv >> 1) * 32, nw = (wv & 1) * 64;
  const int l15 = ln & 15, lg = ln >> 4;
  const bf16* gA = at_t + ((size_t)b * 1024 + i0) * 512;
  const bf16* gB = wp + (size_t)c0 * 512;
  f32x4 acc[2][4] = {};
  async_stage_64x32(gA, As[0], tid);
  async_stage_128x32(gB, Bs[0], tid);
  for (int it = 0; it < 16; ++it) {
    __syncthreads();
    const int cur = it & 1, nxt = cur ^ 1;
    if (it < 15) {
      async_stage_64x32(gA + (it + 1) * 32, As[nxt], tid);
      async_stage_128x32(gB + (it + 1) * 32, Bs[nxt], tid);
    }
    bf16x8 af[2], bfr[4];
#pragma unroll
    for (int mi = 0; mi < 2; ++mi)
      af[mi] = *(const bf16x8*)(&As[cur][(mw + mi * 16 + l15) * 32 + lg * 8]);
#pragma unroll
    for (int nj = 0; nj < 4; ++nj)
      bfr[nj] = *(const bf16x8*)(&Bs[cur][(nw + nj * 16 + l15) * 32 + lg * 8]);
#pragma unroll
    for (int mi = 0; mi < 2; ++mi)
#pragma unroll
      for (int nj = 0; nj < 4; ++nj)
        acc[mi][nj] = MFMA_16x16x32(af[mi], bfr[nj], acc[mi][nj]);
  }
#pragma unroll
  for (int mi = 0; mi < 2; ++mi) {
    const int i = i0 + mw + mi * 16 + lg * 4;
#pragma unroll
    for (int nj = 0; nj < 4; ++nj) {
      const int c = c0 + nw + nj * 16 + l15;
      const float bias = proj_b[c];
      const size_t off = ((size_t)b * 512 + c) * 1024 + i;
      const float4 res = *(const float4*)(x + off);
      f32x4 v = acc[mi][nj];
      float4 ov;
      ov.x = v.x + bias + res.x;
      ov.y = v.y + bias + res.y;
      ov.z = v.z + bias + res.z;
      ov.w = v.w + bias + res.w;
      *(float4*)(out + off) = ov;
    }
  }
}

// ---------------------------------------------------------------------------
extern "C" void kernel_launch(void* const* d_in, const int* in_sizes, int n_in,
                              void* d_out, int out_size, void* d_ws, size_t ws_size,
                              hipStream_t stream) {
  (void)in_sizes; (void)n_in; (void)out_size; (void)ws_size;
  const float* x      = (const float*)d_in[0];
  const float* gn_w   = (const float*)d_in[1];
  const float* gn_b   = (const float*)d_in[2];
  const float* qkv_w  = (const float*)d_in[3];
  const float* qkv_b  = (const float*)d_in[4];
  const float* proj_w = (const float*)d_in[5];
  const float* proj_b = (const float*)d_in[6];
  float* out = (float*)d_out;

  // workspace layout (~100 MB)
  char* ws = (char*)d_ws;
  bf16* wq    = (bf16*)ws;                          // [1536][512]
  bf16* wp    = wq + (size_t)1536 * 512;            // [512][512]
  bf16* xn_t  = wp + (size_t)512 * 512;             // [8][1024][512]
  bf16* qkv_t = xn_t + (size_t)8 * 1024 * 512;      // [8][1024][1536] (Q,K only)
  bf16* at_t  = qkv_t + (size_t)8 * 1024 * 1536;    // [8][1024][512]
  bf16* v_t   = at_t + (size_t)8 * 1024 * 512;      // [8][8][64][1024]

  hipLaunchKernelGGL(gn_fused_kernel, dim3(1280),     dim3(256), 0, stream,
                     x, gn_w, gn_b, qkv_w, proj_w, wq, wp, xn_t);
  hipLaunchKernelGGL(qkv_gemm_kernel, dim3(8, 12, 8), dim3(256), 0, stream,
                     wq, xn_t, qkv_b, qkv_t, v_t);
  hipLaunchKernelGGL(attn_kernel,     dim3(64, 8),    dim3(512), 0, stream,
                     qkv_t, v_t, at_t);
  hipLaunchKernelGGL(proj_gemm_kernel,dim3(16, 4, 8), dim3(256), 0, stream,
                     at_t, wp, proj_b, x, out);
}

// Round 5
// 154.945 us; speedup vs baseline: 1.0144x; 1.0115x over previous
//
#include <hip/hip_runtime.h>

// ---------------------------------------------------------------------------
// AttentionBlock: GroupNorm -> QKV 1x1 conv -> MHA (8 heads, d=64, N=1024)
//               -> proj 1x1 conv -> +residual
// Shapes: B=8, C=512, H=W=32 (N=1024), groups=32, heads=8, hd=64. fp32 I/O.
// R15->R16: attn only. (a) setprio REMOVED (R15 A/B: +2.5us cost -- waves
// are barrier-lockstep, m190 regime). (b) K/V LDS tiles: pad-72 (4-way bank
// conflict on every kf/vf ds_read_b128) -> stride-64 + XOR swizzle
// e ^= (row&7)*8 => 2 lanes/bank = free. (c) staging: reg-staged 4 loads +
// 4 ds_writes -> global_load_lds w=16 with PRE-SWIZZLED global source
// (linear LDS dest + inverse-swz source + swz read, rule #21). LDS 72->64KB.
// Occupancy unchanged (2 blocks/CU, 16 waves/CU -- the R14-measured best).
// ---------------------------------------------------------------------------

typedef __bf16 bf16;
typedef __bf16 bf16x8 __attribute__((ext_vector_type(8)));
typedef __bf16 bf16x4 __attribute__((ext_vector_type(4)));
typedef float  f32x4  __attribute__((ext_vector_type(4)));
typedef float  f32x16 __attribute__((ext_vector_type(16)));
typedef unsigned u32x4 __attribute__((ext_vector_type(4)));

#define MFMA_16x16x32(A, B, C) __builtin_amdgcn_mfma_f32_16x16x32_bf16((A), (B), (C), 0, 0, 0)
#define MFMA_32x32x16(A, B, C) __builtin_amdgcn_mfma_f32_32x32x16_bf16((A), (B), (C), 0, 0, 0)

static __device__ __forceinline__ unsigned cvt_pk_bf16(float a, float b) {
  unsigned r;
  asm("v_cvt_pk_bf16_f32 %0, %1, %2" : "=v"(r) : "v"(a), "v"(b));
  return r;
}

// Stage a 128-row x 32-k bf16 tile (rows stride 512 in global) into LDS via
// async global_load_lds width=16.
static __device__ __forceinline__ void async_stage_128x32(
    const bf16* __restrict__ g0, bf16* lds, int tid) {
  const int wv = tid >> 6, ln = tid & 63;
#pragma unroll
  for (int cc = 0; cc < 2; ++cc) {
    const int c = wv + cc * 4;                       // wave-uniform chunk id
    const bf16* g = g0 + (size_t)(c * 16 + (ln >> 2)) * 512 + (ln & 3) * 8;
    __builtin_amdgcn_global_load_lds(
        (const __attribute__((address_space(1))) void*)g,
        (__attribute__((address_space(3))) void*)(lds + c * 512),
        16, 0, 0);
  }
}

// 64-row variant (one 16-row chunk per wave).
static __device__ __forceinline__ void async_stage_64x32(
    const bf16* __restrict__ g0, bf16* lds, int tid) {
  const int wv = tid >> 6, ln = tid & 63;
  const bf16* g = g0 + (size_t)(wv * 16 + (ln >> 2)) * 512 + (ln & 3) * 8;
  __builtin_amdgcn_global_load_lds(
      (const __attribute__((address_space(1))) void*)g,
      (__attribute__((address_space(3))) void*)(lds + wv * 512),
      16, 0, 0);
}

// ---------------------------------------------------------------------------
// Kernel 1: fused GroupNorm (stats + apply + transpose) and weight cvt.
__global__ __launch_bounds__(256) void gn_fused_kernel(
    const float* __restrict__ x,
    const float* __restrict__ gn_w, const float* __restrict__ gn_b,
    const float* __restrict__ qw, const float* __restrict__ pw,
    bf16* __restrict__ wq, bf16* __restrict__ wp, bf16* __restrict__ xn_t) {
  const int t = threadIdx.x;
  if (blockIdx.x >= 256) {
    const int idx = (blockIdx.x - 256) * 256 + t;    // float4 id
    if (idx < 196608) {                              // 1536*512/4
      float4 v = ((const float4*)qw)[idx];
      bf16x4 o = { (bf16)v.x, (bf16)v.y, (bf16)v.z, (bf16)v.w };
      *(bf16x4*)(&wq[idx * 4]) = o;
    }
    if (idx < 65536) {                               // 512*512/4
      float4 v = ((const float4*)pw)[idx];
      bf16x4 o = { (bf16)v.x, (bf16)v.y, (bf16)v.z, (bf16)v.w };
      *(bf16x4*)(&wp[idx * 4]) = o;
    }
    return;
  }
  const int bg = blockIdx.x;                        // 0..255
  const int b = bg >> 5, g = bg & 31;
  const int c0 = g * 16;
  const float4* p = (const float4*)(x + ((size_t)b * 512 + c0) * 1024);
  float4 v[16];
  float s = 0.f, s2 = 0.f;
#pragma unroll
  for (int i = 0; i < 16; ++i) {                     // c=i, n=4t..4t+3
    v[i] = p[t + 256 * i];
    s  += (v[i].x + v[i].y) + (v[i].z + v[i].w);
    s2 += (v[i].x * v[i].x + v[i].y * v[i].y) + (v[i].z * v[i].z + v[i].w * v[i].w);
  }
#pragma unroll
  for (int d = 1; d < 64; d <<= 1) {
    s  += __shfl_xor(s,  d);
    s2 += __shfl_xor(s2, d);
  }
  __shared__ float as[4], as2[4];
  __shared__ float scs[16], shs[16];
  if ((t & 63) == 0) { as[t >> 6] = s; as2[t >> 6] = s2; }
  __syncthreads();
  if (t < 16) {
    float S  = as[0] + as[1] + as[2] + as[3];
    float S2 = as2[0] + as2[1] + as2[2] + as2[3];
    float m  = S * (1.0f / 16384.0f);
    float rs = rsqrtf(S2 * (1.0f / 16384.0f) - m * m + 1e-5f);
    float sc = rs * gn_w[c0 + t];
    scs[t] = sc;
    shs[t] = gn_b[c0 + t] - m * sc;
  }
  __syncthreads();
  bf16* ob = xn_t + ((size_t)b * 1024 + 4 * t) * 512 + c0;
#pragma unroll
  for (int j = 0; j < 4; ++j) {                      // n = 4t + j
    bf16 tmp[16];
#pragma unroll
    for (int i = 0; i < 16; ++i) {
      float val = (j == 0) ? v[i].x : (j == 1) ? v[i].y : (j == 2) ? v[i].z : v[i].w;
      tmp[i] = (bf16)(val * scs[i] + shs[i]);
    }
    *(bf16x8*)(ob + (size_t)j * 512)     = *(bf16x8*)(tmp);
    *(bf16x8*)(ob + (size_t)j * 512 + 8) = *(bf16x8*)(tmp + 8);
  }
}

// ---------------------------------------------------------------------------
// Kernel 2: QKV GEMM, single-barrier dbuf K-loop (BK=32, 16 iters).
__global__ __launch_bounds__(256) void qkv_gemm_kernel(
    const bf16* __restrict__ W, const bf16* __restrict__ xn_t,
    const float* __restrict__ qkv_b, bf16* __restrict__ qkv_t,
    bf16* __restrict__ v_t) {
  const int n0 = blockIdx.x * 128;
  const int o0 = blockIdx.y * 128;
  const int b  = blockIdx.z;
  __shared__ bf16 As[2][128 * 32];
  __shared__ bf16 Bs[2][128 * 32];
  const int tid = threadIdx.x, ln = tid & 63, wv = tid >> 6;
  const int mw = (wv >> 1) * 64, nw = (wv & 1) * 64;
  const int l15 = ln & 15, lg = ln >> 4;
  const bool isV = (o0 >= 1024);
  const bf16* gA = W + (size_t)o0 * 512;
  const bf16* gB = xn_t + ((size_t)b * 1024 + n0) * 512;
  f32x4 acc[4][4] = {};
  async_stage_128x32(gA, As[0], tid);
  async_stage_128x32(gB, Bs[0], tid);
  for (int it = 0; it < 16; ++it) {
    __syncthreads();                                 // publish buf[cur]
    const int cur = it & 1, nxt = cur ^ 1;
    if (it < 15) {                                   // prefetch overlaps compute
      async_stage_128x32(gA + (it + 1) * 32, As[nxt], tid);
      async_stage_128x32(gB + (it + 1) * 32, Bs[nxt], tid);
    }
    bf16x8 af[4], bfr[4];
#pragma unroll
    for (int mi = 0; mi < 4; ++mi)
      af[mi] = *(const bf16x8*)(&As[cur][(mw + mi * 16 + l15) * 32 + lg * 8]);
#pragma unroll
    for (int nj = 0; nj < 4; ++nj)
      bfr[nj] = *(const bf16x8*)(&Bs[cur][(nw + nj * 16 + l15) * 32 + lg * 8]);
    if (!isV) {
#pragma unroll
      for (int mi = 0; mi < 4; ++mi)
#pragma unroll
        for (int nj = 0; nj < 4; ++nj)
          acc[mi][nj] = MFMA_16x16x32(af[mi], bfr[nj], acc[mi][nj]);
    } else {                                         // swapped: acc = D^T
#pragma unroll
      for (int mi = 0; mi < 4; ++mi)
#pragma unroll
        for (int nj = 0; nj < 4; ++nj)
          acc[mi][nj] = MFMA_16x16x32(bfr[nj], af[mi], acc[mi][nj]);
    }
  }
  if (!isV) {
    const float qs = (o0 < 512) ? 0.125f * 1.44269504089f : 1.0f;
#pragma unroll
    for (int mi = 0; mi < 4; ++mi) {
      const int o = o0 + mw + mi * 16 + lg * 4;
      const float b0 = qkv_b[o], b1 = qkv_b[o + 1], b2 = qkv_b[o + 2], b3 = qkv_b[o + 3];
#pragma unroll
      for (int nj = 0; nj < 4; ++nj) {
        const int n = n0 + nw + nj * 16 + l15;
        f32x4 v = acc[mi][nj];
        bf16x4 st = { (bf16)((v.x + b0) * qs), (bf16)((v.y + b1) * qs),
                      (bf16)((v.z + b2) * qs), (bf16)((v.w + b3) * qs) };
        *(bf16x4*)(&qkv_t[((size_t)b * 1024 + n) * 1536 + o]) = st;
      }
    }
  } else {
    // swapped C-layout: lane holds D[n = nw+nj*16+lg*4+r][o = mw+mi*16+l15]
#pragma unroll
    for (int mi = 0; mi < 4; ++mi) {
      const int o  = o0 + mw + mi * 16 + l15;
      const int hd = o - 1024;                       // h*64 + d
      const float bias = qkv_b[o];
#pragma unroll
      for (int nj = 0; nj < 4; ++nj) {
        const int n = n0 + nw + nj * 16 + lg * 4;
        f32x4 v = acc[mi][nj];
        bf16x4 st = { (bf16)(v.x + bias), (bf16)(v.y + bias),
                      (bf16)(v.z + bias), (bf16)(v.w + bias) };
        *(bf16x4*)(&v_t[((size_t)b * 512 + hd) * 1024 + n]) = st;
      }
    }
  }
}

// ---------------------------------------------------------------------------
// attn staging: per kv-tile, 32 x 1KB global_load_lds chunks (4 per wave).
// LDS tile layout (per buf, per half): K 64x64 bf16 (8KB) then V 64x64
// (8KB), XOR-swizzled: logical (row,e) stored at elem row*64 + (e^((row&7)*8)).
// gload_lds writes linearly (lane ln -> chunk_base + ln*16), so the global
// SOURCE is inverse-swizzled: lane ln covers row g*8+(ln>>3), slot ln&7,
// whose logical elem start = ((ln&7) ^ (ln>>3)) * 8.
static __device__ __forceinline__ void attn_stage(
    const bf16* __restrict__ hk, const bf16* __restrict__ vtb,
    char* bufbase, int it, int wv, int ln) {
  const int hh = wv >> 2;                            // wave stages its half
  const int kt = hh * 8 + it;                        // kv tile index
  const int r8 = ln >> 3;                            // row within 8-row group
  const int e0 = ((ln & 7) ^ r8) * 8;                // inverse-swizzled elem
  char* base = bufbase + hh * 16384;
#pragma unroll
  for (int j = 0; j < 2; ++j) {
    const int g = (wv & 3) * 2 + j;                  // 8-row group 0..7
    const int row = g * 8 + r8;
    const bf16* gk = hk + (size_t)(kt * 64 + row) * 1536 + e0;   // K: row=kv, e=d
    __builtin_amdgcn_global_load_lds(
        (const __attribute__((address_space(1))) void*)gk,
        (__attribute__((address_space(3))) void*)(base + g * 1024),
        16, 0, 0);
    const bf16* gv = vtb + (size_t)row * 1024 + kt * 64 + e0;    // V: row=d, e=kv
    __builtin_amdgcn_global_load_lds(
        (const __attribute__((address_space(1))) void*)gv,
        (__attribute__((address_space(3))) void*)(base + 8192 + g * 1024),
        16, 0, 0);
  }
}

// ---------------------------------------------------------------------------
// Kernel 3: fused attention. 8 waves = 2 kv-halves x 4 q-subtiles(32 q).
// half h sweeps kv tiles [h*8, h*8+8). 32x32x16 MFMA, swapped QK^T; exp2 in
// regs; P->B-frag via v_cvt_pk_bf16_f32 + v_permlane32_swap_b32. K/V
// double-buffered (2 x 32768 B), ONE barrier per tile, gload_lds prefetch
// issued right after the barrier. Halves combine O/l via f32 LDS exchange.
__global__ __launch_bounds__(512, 4) void attn_kernel(
    const bf16* __restrict__ qkv_t, const bf16* __restrict__ v_t,
    bf16* __restrict__ at_t) {
  const int qt = blockIdx.y;                        // 0..7 (128 q each)
  const int b  = blockIdx.x >> 3;
  const int h  = blockIdx.x & 7;
  __shared__ __align__(16) char smem[65536];        // 2 bufs x 2 halves x (K+V 64x64)
  const int tid = threadIdx.x, ln = tid & 63, wv = tid >> 6;
  const int half = wv >> 2, w4 = wv & 3;
  const int l31 = ln & 31, hi = ln >> 5;
  const bf16* hq  = qkv_t + (size_t)b * 1024 * 1536 + h * 64;
  const bf16* hk  = hq + 512;
  const bf16* vtb = v_t + (size_t)(b * 8 + h) * 64 * 1024;

  const int qb = qt * 128 + w4 * 32;
  // Q B-fragments: lane holds q=l31, d = ks*16 + hi*8 + j
  bf16x8 qf[4];
#pragma unroll
  for (int ks = 0; ks < 4; ++ks)
    qf[ks] = *(const bf16x8*)(hq + (size_t)(qb + l31) * 1536 + ks * 16 + hi * 8);

  f32x16 oacc[2] = {};                              // O^T[d-tile][q]
  float lst = 0.f;

  attn_stage(hk, vtb, smem, 0, wv, ln);             // prologue: tile 0 -> buf0

  for (int i = 0; i < 8; ++i) {
    __syncthreads();                                 // drains vmcnt, publish buf[i&1]
    if (i < 7)                                       // prefetch next tile -> other buf
      attn_stage(hk, vtb, smem + ((i + 1) & 1) * 32768, i + 1, wv, ln);
    const bf16* Kt = (const bf16*)(smem + (i & 1) * 32768 + half * 16384);
    const bf16* Vt = Kt + 64 * 64;

#pragma unroll
    for (int kk = 0; kk < 2; ++kk) {
      const int kvb = kk * 32;
      const int krow = kvb + l31;
      const int ksw = (krow & 7) * 8;
      f32x16 st = {};
#pragma unroll
      for (int ks = 0; ks < 4; ++ks) {
        bf16x8 kf = *(const bf16x8*)(&Kt[krow * 64 + ((ks * 16 + hi * 8) ^ ksw)]);
        st = MFMA_32x32x16(kf, qf[ks], st);
      }
#pragma unroll
      for (int r = 0; r < 16; ++r) st[r] = exp2f(st[r]);
      lst += ((st[0] + st[1]) + (st[2] + st[3])) + ((st[4] + st[5]) + (st[6] + st[7]))
           + ((st[8] + st[9]) + (st[10] + st[11])) + ((st[12] + st[13]) + (st[14] + st[15]));
#pragma unroll
      for (int t = 0; t < 2; ++t) {
        // own regs hold kv rows crow(r,hi); swap lane-halves to build B-frag
        // (lane needs kv = t*16 + hi*8 + j). After swap: {x0,x1,y0,y1} are
        // the 4 B-frag words in order.
        unsigned x0 = cvt_pk_bf16(st[t * 8 + 0], st[t * 8 + 1]);
        unsigned x1 = cvt_pk_bf16(st[t * 8 + 2], st[t * 8 + 3]);
        unsigned y0 = cvt_pk_bf16(st[t * 8 + 4], st[t * 8 + 5]);
        unsigned y1 = cvt_pk_bf16(st[t * 8 + 6], st[t * 8 + 7]);
        asm("v_permlane32_swap_b32 %0, %1" : "+v"(x0), "+v"(y0));
        asm("v_permlane32_swap_b32 %0, %1" : "+v"(x1), "+v"(y1));
        u32x4 pu = { x0, x1, y0, y1 };
        bf16x8 pb = __builtin_bit_cast(bf16x8, pu);
#pragma unroll
        for (int dt = 0; dt < 2; ++dt) {
          const int vrow = dt * 32 + l31;
          bf16x8 vf = *(const bf16x8*)(
              &Vt[vrow * 64 + ((kvb + t * 16 + hi * 8) ^ ((vrow & 7) * 8))]);
          oacc[dt] = MFMA_32x32x16(vf, pb, oacc[dt]);
        }
      }
    }
  }

  // lanes l / l+32 hold complementary kv rows for the same q (within half)
  const float lf = lst + __shfl_xor(lst, 32);

  // combine halves: half 1 publishes O^T + l via LDS; half 0 merges+stores.
  float* MB  = (float*)smem;                        // [w4][32 q][68 d-stride]
  float* MLb = (float*)(smem + 34816);              // [w4][32]
  __syncthreads();
  if (half == 1) {
    float* mb = MB + w4 * (32 * 68);
#pragma unroll
    for (int dt = 0; dt < 2; ++dt)
#pragma unroll
      for (int rr = 0; rr < 4; ++rr) {
        f32x4 v = { oacc[dt][rr * 4 + 0], oacc[dt][rr * 4 + 1],
                    oacc[dt][rr * 4 + 2], oacc[dt][rr * 4 + 3] };
        *(f32x4*)(mb + l31 * 68 + dt * 32 + rr * 8 + hi * 4) = v;
      }
    if (hi == 0) MLb[w4 * 32 + l31] = lf;
  }
  __syncthreads();
  if (half == 0) {
    const float* mb = MB + w4 * (32 * 68);
    const float inv = 1.0f / (lf + MLb[w4 * 32 + l31]);
    const int q = qb + l31;
    bf16* ob = at_t + ((size_t)b * 1024 + q) * 512 + h * 64;
#pragma unroll
    for (int dt = 0; dt < 2; ++dt)
#pragma unroll
      for (int rr = 0; rr < 4; ++rr) {
        f32x4 obv = *(const f32x4*)(mb + l31 * 68 + dt * 32 + rr * 8 + hi * 4);
        bf16x4 ov = { (bf16)((oacc[dt][rr * 4 + 0] + obv[0]) * inv),
                      (bf16)((oacc[dt][rr * 4 + 1] + obv[1]) * inv),
                      (bf16)((oacc[dt][rr * 4 + 2] + obv[2]) * inv),
                      (bf16)((oacc[dt][rr * 4 + 3] + obv[3]) * inv) };
        *(bf16x4*)(ob + dt * 32 + rr * 8 + hi * 4) = ov;
      }
  }
}

// ---------------------------------------------------------------------------
// Kernel 4: proj GEMM + bias + residual. BM=64, single-barrier dbuf (BK=32).
__global__ __launch_bounds__(256) void proj_gemm_kernel(
    const bf16* __restrict__ at_t, const bf16* __restrict__ wp,
    const float* __restrict__ proj_b, const float* __restrict__ x,
    float* __restrict__ out) {
  const int i0 = blockIdx.x * 64;                   // token tile (64)
  const int c0 = blockIdx.y * 128;                  // out-channel tile (128)
  const int b  = blockIdx.z;
  __shared__ bf16 As[2][64 * 32];
  __shared__ bf16 Bs[2][128 * 32];
  const int tid = threadIdx.x, ln = tid & 63, wv = tid >> 6;
  const int mw = (wv >> 1) * 32, nw = (wv & 1) * 64;
  const int l15 = ln & 15, lg = ln >> 4;
  const bf16* gA = at_t + ((size_t)b * 1024 + i0) * 512;
  const bf16* gB = wp + (size_t)c0 * 512;
  f32x4 acc[2][4] = {};
  async_stage_64x32(gA, As[0], tid);
  async_stage_128x32(gB, Bs[0], tid);
  for (int it = 0; it < 16; ++it) {
    __syncthreads();
    const int cur = it & 1, nxt = cur ^ 1;
    if (it < 15) {
      async_stage_64x32(gA + (it + 1) * 32, As[nxt], tid);
      async_stage_128x32(gB + (it + 1) * 32, Bs[nxt], tid);
    }
    bf16x8 af[2], bfr[4];
#pragma unroll
    for (int mi = 0; mi < 2; ++mi)
      af[mi] = *(const bf16x8*)(&As[cur][(mw + mi * 16 + l15) * 32 + lg * 8]);
#pragma unroll
    for (int nj = 0; nj < 4; ++nj)
      bfr[nj] = *(const bf16x8*)(&Bs[cur][(nw + nj * 16 + l15) * 32 + lg * 8]);
#pragma unroll
    for (int mi = 0; mi < 2; ++mi)
#pragma unroll
      for (int nj = 0; nj < 4; ++nj)
        acc[mi][nj] = MFMA_16x16x32(af[mi], bfr[nj], acc[mi][nj]);
  }
#pragma unroll
  for (int mi = 0; mi < 2; ++mi) {
    const int i = i0 + mw + mi * 16 + lg * 4;
#pragma unroll
    for (int nj = 0; nj < 4; ++nj) {
      const int c = c0 + nw + nj * 16 + l15;
      const float bias = proj_b[c];
      const size_t off = ((size_t)b * 512 + c) * 1024 + i;
      const float4 res = *(const float4*)(x + off);
      f32x4 v = acc[mi][nj];
      float4 ov;
      ov.x = v.x + bias + res.x;
      ov.y = v.y + bias + res.y;
      ov.z = v.z + bias + res.z;
      ov.w = v.w + bias + res.w;
      *(float4*)(out + off) = ov;
    }
  }
}

// ---------------------------------------------------------------------------
extern "C" void kernel_launch(void* const* d_in, const int* in_sizes, int n_in,
                              void* d_out, int out_size, void* d_ws, size_t ws_size,
                              hipStream_t stream) {
  (void)in_sizes; (void)n_in; (void)out_size; (void)ws_size;
  const float* x      = (const float*)d_in[0];
  const float* gn_w   = (const float*)d_in[1];
  const float* gn_b   = (const float*)d_in[2];
  const float* qkv_w  = (const float*)d_in[3];
  const float* qkv_b  = (const float*)d_in[4];
  const float* proj_w = (const float*)d_in[5];
  const float* proj_b = (const float*)d_in[6];
  float* out = (float*)d_out;

  // workspace layout (~100 MB)
  char* ws = (char*)d_ws;
  bf16* wq    = (bf16*)ws;                          // [1536][512]
  bf16* wp    = wq + (size_t)1536 * 512;            // [512][512]
  bf16* xn_t  = wp + (size_t)512 * 512;             // [8][1024][512]
  bf16* qkv_t = xn_t + (size_t)8 * 1024 * 512;      // [8][1024][1536] (Q,K only)
  bf16* at_t  = qkv_t + (size_t)8 * 1024 * 1536;    // [8][1024][512]
  bf16* v_t   = at_t + (size_t)8 * 1024 * 512;      // [8][8][64][1024]

  hipLaunchKernelGGL(gn_fused_kernel, dim3(1280),     dim3(256), 0, stream,
                     x, gn_w, gn_b, qkv_w, proj_w, wq, wp, xn_t);
  hipLaunchKernelGGL(qkv_gemm_kernel, dim3(8, 12, 8), dim3(256), 0, stream,
                     wq, xn_t, qkv_b, qkv_t, v_t);
  hipLaunchKernelGGL(attn_kernel,     dim3(64, 8),    dim3(512), 0, stream,
                     qkv_t, v_t, at_t);
  hipLaunchKernelGGL(proj_gemm_kernel,dim3(16, 4, 8), dim3(256), 0, stream,
                     at_t, wp, proj_b, x, out);
}